// Round 5
// baseline (15449.927 us; speedup 1.0000x reference)
//
#include <hip/hip_runtime.h>
#include <hip/hip_bf16.h>

// ---------------- problem constants ----------------
#define B_   1024
#define T_   365
#define D_   24
#define H_   128

// bf16 weight arena layout (ushort element offsets)
#define WIH1P_OFF 0         // [384][32]  (24 cols + zero pad)
#define WIH2P_OFF 12288     // [384][32]  (24 x cols, col24 = lai weight, pad)
#define WHH_OFF   24576     // 4 x [384][128]
#define WIH3_OFF  221184    // [384][256]
#define WIH4_OFF  319488    // [384][256]
#define WS_ELEMS  417792

typedef __attribute__((ext_vector_type(8))) short bf16x8;
typedef __attribute__((ext_vector_type(4))) float f32x4;

__device__ __align__(16) unsigned short g_ws[WS_ELEMS];

#define MFMA(a, b, c) __builtin_amdgcn_mfma_f32_16x16x32_bf16((a), (b), (c), 0, 0, 0)

__device__ __forceinline__ bf16x8 ldw(const unsigned short* p) {
  return *(const bf16x8*)p;
}
__device__ __forceinline__ unsigned short f2b(float f) {
  union { __hip_bfloat16 h; unsigned short u; } cv;
  cv.h = __float2bfloat16(f);   // RNE
  return cv.u;
}
__device__ __forceinline__ float b2f(unsigned short u) {
  union { float f; unsigned int u32; } cv;
  cv.u32 = ((unsigned int)u) << 16;
  return cv.f;
}
__device__ __forceinline__ float sigmoidf_(float x) { return 1.f / (1.f + __expf(-x)); }
__device__ __forceinline__ float tanhf_(float x) {
  float e = __expf(2.f * x);
  return 1.f - 2.f / (e + 1.f);   // handles +-inf limits correctly
}

// ---------------- prologue: fp32 -> padded bf16 weights ----------------
__global__ void prep_weights(const float* wih1, const float* wih2,
                             const float* whh1, const float* whh2,
                             const float* whh3, const float* whh4,
                             const float* wih3, const float* wih4) {
  int i = blockIdx.x * blockDim.x + threadIdx.x;
  if (i >= WS_ELEMS) return;
  float v;
  if (i < 12288) {                       // Wih1 padded [384][32]
    int r = i >> 5, c = i & 31;
    v = (c < 24) ? wih1[r * 24 + c] : 0.f;
  } else if (i < 24576) {                // Wih2 padded [384][32] (col 24 = lai)
    int j = i - 12288;
    int r = j >> 5, c = j & 31;
    v = (c < 25) ? wih2[r * 25 + c] : 0.f;
  } else if (i < 221184) {               // Whh1..4 [384][128]
    int j = i - 24576;
    if      (j < 49152)  v = whh1[j];
    else if (j < 98304)  v = whh2[j - 49152];
    else if (j < 147456) v = whh3[j - 98304];
    else                 v = whh4[j - 147456];
  } else if (i < 319488) {               // Wih3 [384][256]
    v = wih3[i - 221184];
  } else {                               // Wih4 [384][256]
    v = wih4[i - 319488];
  }
  g_ws[i] = f2b(v);
}

// ---------------- main persistent kernel ----------------
struct GruParams {
  const float* x;
  const float* bih[4];
  const float* bhh[4];
  const float* wfc[4];
  const float* bfc[4];
  float* out;        // [B][T][9]
  float* hf[4];      // [B][128] final states
  float* hT[4];      // [B][T][128]
};

// dynamic LDS layout (bytes)
#define L_HFRAG 0u        // ushort [2][4][16][16][8] = 32768
#define L_XA    32768u    // ushort [4][16][8]        = 1024
#define L_PSUM  33792u    // f32x4  [8][7][64]        = 57344
#define SMEMB   91136u

__global__ __launch_bounds__(1024) void gru_main(GruParams p) {
  extern __shared__ __align__(16) unsigned char smem[];
  unsigned short (*hfrag)[4][16][16][8] =
      (unsigned short (*)[4][16][16][8])(smem + L_HFRAG);   // [2][cell][kg][m][e]
  unsigned short (*xa)[16][8] =
      (unsigned short (*)[16][8])(smem + L_XA);             // [kg][m][e]
  f32x4* psum = (f32x4*)(smem + L_PSUM);

  const int tid  = threadIdx.x;
  const int lane = tid & 63;
  const int w    = tid >> 6;       // 0..15
  const int cg   = w & 7;          // 16-col group
  const int ks   = w >> 3;         // K-half
  const int nlo  = lane & 15;
  const int khi  = lane >> 4;      // 0..3
  const int nh   = cg * 16 + nlo;  // hidden column this lane owns
  const int b0   = blockIdx.x * 16;
  const int k8   = khi * 8;
  const int kcb  = ks * 2;         // base kc for this K-half

#define PS(slot) psum[((cg) * 7 + (slot)) * 64 + lane]

  for (int i = tid; i < 2 * 4 * 16 * 16 * 8; i += 1024) ((unsigned short*)hfrag)[i] = 0;
  // stage x for t=0 (col24 = lai = 0; cols 25..31 stay 0 forever)
  if (tid < 512) {
    int row = tid >> 5, col = tid & 31;
    float v = (col < 24) ? p.x[(size_t)(b0 + row) * (T_ * D_) + col] : 0.f;
    xa[col >> 3][row][col & 7] = f2b(v);
  }

  // fp32 hidden-state carry (valid in ks==0 waves): hreg[c][q] == h_c[khi*4+q][nh]
  float hreg[4][4];
#pragma unroll
  for (int c = 0; c < 4; ++c)
#pragma unroll
    for (int q = 0; q < 4; ++q) hreg[c][q] = 0.f;

  // hoisted biases (used by ks==0 only; harmless elsewhere)
  float brz[4][2], bin[4], bhn[4];
#pragma unroll
  for (int c = 0; c < 4; ++c) {
    brz[c][0] = p.bih[c][nh] + p.bhh[c][nh];
    brz[c][1] = p.bih[c][128 + nh] + p.bhh[c][128 + nh];
    bin[c]    = p.bih[c][256 + nh];
    bhn[c]    = p.bhh[c][256 + nh];
  }

  // weight base pointers (per lane); fragment offsets are compile-time immediates
  const unsigned short* pwx = g_ws + (ks ? WIH2P_OFF : WIH1P_OFF) + nh * 32 + k8;
  const unsigned short* pwh = g_ws + WHH_OFF + nh * 128 + k8;        // + c*49152
  const unsigned short* pw3 = g_ws + WIH3_OFF + nh * 256 + k8 + (ks ? 128 : 0);
  const unsigned short* pw4 = g_ws + WIH4_OFF + nh * 256 + k8 + (ks ? 128 : 0);

  // FC assignment: 144 threads = 16 rows x 9 outputs (all in ks==0 waves)
  const bool fc_on = (tid < 144);
  const int foi = tid % 9;
  int frow = 0, fcell = 0;
  const float4* fw4 = nullptr;
  float fb = 0.f;
  if (fc_on) {
    frow = tid / 9;
    const float* fw;
    if (foi == 0)     { fcell = 0; fw = p.wfc[0];                   fb = p.bfc[0][0]; }
    else if (foi < 4) { fcell = 1; fw = p.wfc[1] + (foi - 1) * 128; fb = p.bfc[1][foi - 1]; }
    else if (foi < 7) { fcell = 2; fw = p.wfc[2] + (foi - 4) * 128; fb = p.bfc[2][foi - 4]; }
    else              { fcell = 3; fw = p.wfc[3] + (foi - 7) * 128; fb = p.bfc[3][foi - 7]; }
    fw4 = (const float4*)fw;
  }

  __syncthreads();

  for (int t = 0; t < T_; ++t) {
    const int ib = t & 1, ob = ib ^ 1;

    // ================= stage A: cells 1 & 2 (K-split) =================
    {
      bf16x8 ax = ldw(&xa[khi][nlo][0]);
      bf16x8 a1[2], a2[2];
#pragma unroll
      for (int j = 0; j < 2; ++j) {
        a1[j] = ldw(&hfrag[ib][0][(kcb + j) * 4 + khi][nlo][0]);
        a2[j] = ldw(&hfrag[ib][1][(kcb + j) * 4 + khi][nlo][0]);
      }
      bf16x8 wx[3], wh1[2][3], wh2[2][3];
#pragma unroll
      for (int g = 0; g < 3; ++g) wx[g] = ldw(pwx + g * 4096);
#pragma unroll
      for (int j = 0; j < 2; ++j)
#pragma unroll
        for (int g = 0; g < 3; ++g) {
          wh1[j][g] = ldw(pwh + g * 16384 + (kcb + j) * 32);
          wh2[j][g] = ldw(pwh + 49152 + g * 16384 + (kcb + j) * 32);
        }
      f32x4 R1 = {0.f,0.f,0.f,0.f}, Z1 = R1, H1 = R1;
      f32x4 R2 = R1, Z2 = R1, H2 = R1, Ig = R1;
      if (!ks) { R1 = MFMA(ax, wx[0], R1); Z1 = MFMA(ax, wx[1], Z1); }
      else     { R2 = MFMA(ax, wx[0], R2); Z2 = MFMA(ax, wx[1], Z2); }
      Ig = MFMA(ax, wx[2], Ig);   // gi_n for cell (1+ks)
#pragma unroll
      for (int j = 0; j < 2; ++j) {
        R1 = MFMA(a1[j], wh1[j][0], R1);
        Z1 = MFMA(a1[j], wh1[j][1], Z1);
        H1 = MFMA(a1[j], wh1[j][2], H1);
        R2 = MFMA(a2[j], wh2[j][0], R2);
        Z2 = MFMA(a2[j], wh2[j][1], Z2);
        H2 = MFMA(a2[j], wh2[j][2], H2);
      }
      if (ks) {
        PS(0) = R1; PS(1) = Z1; PS(2) = H1;
        PS(3) = R2; PS(4) = Z2; PS(5) = H2; PS(6) = Ig;
      }
      __syncthreads();   // (1)
      if (!ks) {
        R1 += PS(0); Z1 += PS(1); H1 += PS(2);
        R2 += PS(3); Z2 += PS(4); H2 += PS(5);
        f32x4 I2 = PS(6);
#pragma unroll
        for (int q = 0; q < 4; ++q) {
          int m = khi * 4 + q;
          {
            float r = sigmoidf_(R1[q] + brz[0][0]);
            float z = sigmoidf_(Z1[q] + brz[0][1]);
            float n = tanhf_(Ig[q] + bin[0] + r * (H1[q] + bhn[0]));
            float hnew = (1.f - z) * n + z * hreg[0][q];
            hreg[0][q] = hnew;
            hfrag[ob][0][nh >> 3][m][nh & 7] = f2b(hnew);
          }
          {
            float r = sigmoidf_(R2[q] + brz[1][0]);
            float z = sigmoidf_(Z2[q] + brz[1][1]);
            float n = tanhf_(I2[q] + bin[1] + r * (H2[q] + bhn[1]));
            float hnew = (1.f - z) * n + z * hreg[1][q];
            hreg[1][q] = hnew;
            hfrag[ob][1][nh >> 3][m][nh & 7] = f2b(hnew);
          }
        }
      }
    }
    __syncthreads();   // (2)

    // ================= stage B: cell 3 (K-split) =================
    {
      // A-operands: ks0 -> h1_new (all 4 kc), ks1 -> h2_new (all 4 kc)
      bf16x8 hsrc[4], a3[2];
#pragma unroll
      for (int kc = 0; kc < 4; ++kc)
        hsrc[kc] = ldw(&hfrag[ob][ks][kc * 4 + khi][nlo][0]);
#pragma unroll
      for (int j = 0; j < 2; ++j)
        a3[j] = ldw(&hfrag[ib][2][(kcb + j) * 4 + khi][nlo][0]);
      bf16x8 wv[4][3], wh[2][3];
#pragma unroll
      for (int kc = 0; kc < 4; ++kc)
#pragma unroll
        for (int g = 0; g < 3; ++g) wv[kc][g] = ldw(pw3 + g * 32768 + kc * 32);
#pragma unroll
      for (int j = 0; j < 2; ++j)
#pragma unroll
        for (int g = 0; g < 3; ++g)
          wh[j][g] = ldw(pwh + 2 * 49152 + g * 16384 + (kcb + j) * 32);
      f32x4 R = {0.f,0.f,0.f,0.f}, Z = R, I = R, Hh = R;
#pragma unroll
      for (int kc = 0; kc < 4; ++kc) {
        R = MFMA(hsrc[kc], wv[kc][0], R);
        Z = MFMA(hsrc[kc], wv[kc][1], Z);
        I = MFMA(hsrc[kc], wv[kc][2], I);
      }
#pragma unroll
      for (int j = 0; j < 2; ++j) {
        R  = MFMA(a3[j], wh[j][0], R);
        Z  = MFMA(a3[j], wh[j][1], Z);
        Hh = MFMA(a3[j], wh[j][2], Hh);
      }
      if (ks) { PS(0) = R; PS(1) = Z; PS(2) = I; PS(3) = Hh; }
      __syncthreads();   // (3)
      if (!ks) {
        R += PS(0); Z += PS(1); I += PS(2); Hh += PS(3);
#pragma unroll
        for (int q = 0; q < 4; ++q) {
          int m = khi * 4 + q;
          float r = sigmoidf_(R[q] + brz[2][0]);
          float z = sigmoidf_(Z[q] + brz[2][1]);
          float n = tanhf_(I[q] + bin[2] + r * (Hh[q] + bhn[2]));
          float hnew = (1.f - z) * n + z * hreg[2][q];
          hreg[2][q] = hnew;
          hfrag[ob][2][nh >> 3][m][nh & 7] = f2b(hnew);
        }
      }
    }
    __syncthreads();   // (4)

    // ================= stage C: cell 4 (K-split) =================
    {
      // A-operands: ks0 -> h1_new, ks1 -> h3_new
      bf16x8 hsrc[4], a4[2];
#pragma unroll
      for (int kc = 0; kc < 4; ++kc)
        hsrc[kc] = ldw(&hfrag[ob][ks * 2][kc * 4 + khi][nlo][0]);
#pragma unroll
      for (int j = 0; j < 2; ++j)
        a4[j] = ldw(&hfrag[ib][3][(kcb + j) * 4 + khi][nlo][0]);
      bf16x8 wv[4][3], wh[2][3];
#pragma unroll
      for (int kc = 0; kc < 4; ++kc)
#pragma unroll
        for (int g = 0; g < 3; ++g) wv[kc][g] = ldw(pw4 + g * 32768 + kc * 32);
#pragma unroll
      for (int j = 0; j < 2; ++j)
#pragma unroll
        for (int g = 0; g < 3; ++g)
          wh[j][g] = ldw(pwh + 3 * 49152 + g * 16384 + (kcb + j) * 32);
      f32x4 R = {0.f,0.f,0.f,0.f}, Z = R, I = R, Hh = R;
#pragma unroll
      for (int kc = 0; kc < 4; ++kc) {
        R = MFMA(hsrc[kc], wv[kc][0], R);
        Z = MFMA(hsrc[kc], wv[kc][1], Z);
        I = MFMA(hsrc[kc], wv[kc][2], I);
      }
#pragma unroll
      for (int j = 0; j < 2; ++j) {
        R  = MFMA(a4[j], wh[j][0], R);
        Z  = MFMA(a4[j], wh[j][1], Z);
        Hh = MFMA(a4[j], wh[j][2], Hh);
      }
      if (ks) { PS(0) = R; PS(1) = Z; PS(2) = I; PS(3) = Hh; }
      __syncthreads();   // (5)
      if (!ks) {
        R += PS(0); Z += PS(1); I += PS(2); Hh += PS(3);
#pragma unroll
        for (int q = 0; q < 4; ++q) {
          int m = khi * 4 + q;
          float r = sigmoidf_(R[q] + brz[3][0]);
          float z = sigmoidf_(Z[q] + brz[3][1]);
          float n = tanhf_(I[q] + bin[3] + r * (Hh[q] + bhn[3]));
          float hnew = (1.f - z) * n + z * hreg[3][q];
          hreg[3][q] = hnew;
          hfrag[ob][3][nh >> 3][m][nh & 7] = f2b(hnew);
        }
      }
    }
    __syncthreads();   // (6)

    // ========= FC heads + hT stores + x staging (one phase) =========
    if (!ks) {
      // ks0 threads hold the fp32 h for this step: store hT
#pragma unroll
      for (int c = 0; c < 4; ++c)
#pragma unroll
        for (int q = 0; q < 4; ++q) {
          int m = khi * 4 + q;
          p.hT[c][(size_t)(b0 + m) * (T_ * H_) + (size_t)t * H_ + nh] = hreg[c][q];
        }
    }
    if (fc_on) {
      const unsigned short* hb = &hfrag[ob][fcell][0][frow][0];
      float acc = fb;
#pragma unroll
      for (int kg = 0; kg < 16; ++kg) {
        bf16x8 hv = *(const bf16x8*)(hb + kg * 128);
        float4 wA = fw4[kg * 2], wB = fw4[kg * 2 + 1];
        acc += b2f((unsigned short)hv[0]) * wA.x + b2f((unsigned short)hv[1]) * wA.y +
               b2f((unsigned short)hv[2]) * wA.z + b2f((unsigned short)hv[3]) * wA.w +
               b2f((unsigned short)hv[4]) * wB.x + b2f((unsigned short)hv[5]) * wB.y +
               b2f((unsigned short)hv[6]) * wB.z + b2f((unsigned short)hv[7]) * wB.w;
      }
      p.out[(size_t)(b0 + frow) * (T_ * 9) + t * 9 + foi] = acc;
      if (foi == 7) xa[3][frow][0] = f2b(acc);   // lai for next step (o4 col 0)
    } else if (tid >= 512 && t + 1 < T_) {
      // ks1 waves: stage x_{t+1} cols 0..23 (col 24 written by FC; 25..31 stay 0)
      for (int i = tid - 512; i < 16 * 24; i += 512) {
        int row = i / 24, col = i % 24;
        xa[col >> 3][row][col & 7] =
            f2b(p.x[(size_t)(b0 + row) * (T_ * D_) + (size_t)(t + 1) * D_ + col]);
      }
    }
    __syncthreads();   // (7)
  }

  // ---- final hidden states (fp32 from register carry, ks0 waves) ----
  if (!ks) {
#pragma unroll
    for (int c = 0; c < 4; ++c)
#pragma unroll
      for (int q = 0; q < 4; ++q)
        p.hf[c][(size_t)(b0 + khi * 4 + q) * H_ + nh] = hreg[c][q];
  }
}

// ---------------- launcher ----------------
extern "C" void kernel_launch(void* const* d_in, const int* in_sizes, int n_in,
                              void* d_out, int out_size, void* d_ws, size_t ws_size,
                              hipStream_t stream) {
  (void)in_sizes; (void)n_in; (void)d_ws; (void)ws_size; (void)out_size;
  const float* x    = (const float*)d_in[0];
  const float* wih1 = (const float*)d_in[1];
  const float* whh1 = (const float*)d_in[2];
  const float* wih2 = (const float*)d_in[7];
  const float* whh2 = (const float*)d_in[8];
  const float* wih3 = (const float*)d_in[13];
  const float* whh3 = (const float*)d_in[14];
  const float* wih4 = (const float*)d_in[19];
  const float* whh4 = (const float*)d_in[20];

  prep_weights<<<(WS_ELEMS + 255) / 256, 256, 0, stream>>>(wih1, wih2, whh1, whh2,
                                                           whh3, whh4, wih3, wih4);

  GruParams p;
  p.x = x;
  for (int c = 0; c < 4; ++c) {
    p.bih[c] = (const float*)d_in[3 + 6 * c];
    p.bhh[c] = (const float*)d_in[4 + 6 * c];
    p.wfc[c] = (const float*)d_in[5 + 6 * c];
    p.bfc[c] = (const float*)d_in[6 + 6 * c];
  }
  float* out = (float*)d_out;
  p.out = out;                                    // B*T*9 = 3,363,840
  const size_t HF_OFF = (size_t)B_ * T_ * 9;      // 3,363,840
  const size_t HT_OFF = HF_OFF + 4ull * B_ * H_;  // 3,888,128
  const size_t HT_SZ  = (size_t)B_ * T_ * H_;     // 47,841,280
  for (int c = 0; c < 4; ++c) {
    p.hf[c] = out + HF_OFF + (size_t)c * B_ * H_;
    p.hT[c] = out + HT_OFF + (size_t)c * HT_SZ;
  }

  hipFuncSetAttribute(reinterpret_cast<const void*>(gru_main),
                      hipFuncAttributeMaxDynamicSharedMemorySize, (int)SMEMB);
  gru_main<<<64, 1024, SMEMB, stream>>>(p);
}

// Round 6
// 9838.726 us; speedup vs baseline: 1.5703x; 1.5703x over previous
//
#include <hip/hip_runtime.h>
#include <hip/hip_bf16.h>

// ---------------- problem constants ----------------
#define B_   1024
#define T_   365
#define D_   24
#define H_   128

// g_ws: bf16 weights, fragment-major TILE order (26 tiles):
//  t0: wih1p [k32 x 384rows] 24KB   t1: wih2p 24KB (k=24 -> lai col)
//  t2-4: whh1 r/z/n gate-tiles [128rows][128k] 32KB each
//  t5-7: whh2   t8-13: wih3 (ka r,z,n | kb r,z,n)   t14-16: whh3
//  t17-22: wih4 (ka | kb)   t23-25: whh4
#define WS_ELEMS 417792
#define TBQ(q) (24576 + ((q) - 2) * 16384)

typedef __attribute__((ext_vector_type(8))) short bf16x8;
typedef __attribute__((ext_vector_type(4))) float f32x4;

__device__ __align__(16) unsigned short g_ws[WS_ELEMS];

#define MFMA(a, b, c) __builtin_amdgcn_mfma_f32_16x16x32_bf16((a), (b), (c), 0, 0, 0)

// counted-vmcnt phase sync: wait own tile loads, raw barrier (no vmcnt(0) drain)
#define SYNC_V(N) do { \
  __builtin_amdgcn_sched_barrier(0); \
  asm volatile("s_waitcnt vmcnt(" #N ") lgkmcnt(0)" ::: "memory"); \
  __builtin_amdgcn_s_barrier(); \
  __builtin_amdgcn_sched_barrier(0); \
} while (0)

#define SYNC_NV() do { \
  __builtin_amdgcn_sched_barrier(0); \
  asm volatile("s_waitcnt lgkmcnt(0)" ::: "memory"); \
  __builtin_amdgcn_s_barrier(); \
  __builtin_amdgcn_sched_barrier(0); \
} while (0)

__device__ __forceinline__ bf16x8 ldw(const unsigned short* p) {
  return *(const bf16x8*)p;
}
__device__ __forceinline__ unsigned short f2b(float f) {
  union { __hip_bfloat16 h; unsigned short u; } cv;
  cv.h = __float2bfloat16(f);   // RNE
  return cv.u;
}
__device__ __forceinline__ float sigmoidf_(float x) { return 1.f / (1.f + __expf(-x)); }
__device__ __forceinline__ float tanhf_(float x) {
  float e = __expf(2.f * x);
  return 1.f - 2.f / (e + 1.f);
}

// async DMA: wave wid copies NCH KB, linear; lane contributes 16B per instr
template <int NCH>
__device__ __forceinline__ void dma_tile(const unsigned short* gsrc, unsigned short* lbuf,
                                         int wid, int lane) {
  const char* g = (const char*)gsrc + wid * (NCH * 1024) + lane * 16;
  char* l = (char*)lbuf + wid * (NCH * 1024);
#pragma unroll
  for (int j = 0; j < NCH; ++j)
    __builtin_amdgcn_global_load_lds(
        (const __attribute__((address_space(1))) void*)(g + j * 1024),
        (__attribute__((address_space(3))) void*)(l + j * 1024), 16, 0, 0);
}

// 4-MFMA gate-tile accumulate
__device__ __forceinline__ f32x4 gtile(const unsigned short* buf, int woff,
                                       const bf16x8* a, f32x4 acc) {
#pragma unroll
  for (int kc = 0; kc < 4; ++kc)
    acc = MFMA(a[kc], *(const bf16x8*)(buf + woff + kc * 4096), acc);
  return acc;
}

// ---------------- prologue: fp32 -> fragment-major bf16 tiles ----------------
__global__ void prep_weights(const float* wih1, const float* wih2,
                             const float* whh1, const float* whh2,
                             const float* whh3, const float* whh4,
                             const float* wih3, const float* wih4) {
  int i = blockIdx.x * blockDim.x + threadIdx.x;
  if (i >= WS_ELEMS) return;
  float v = 0.f;
  if (i < 12288) {                 // t0: (kg*384 + row)*8 + e
    int kg = i / 3072, rem = i % 3072, r = rem >> 3, e = rem & 7, k = kg * 8 + e;
    v = (k < 24) ? wih1[r * 24 + k] : 0.f;
  } else if (i < 24576) {          // t1
    int j = i - 12288;
    int kg = j / 3072, rem = j % 3072, r = rem >> 3, e = rem & 7, k = kg * 8 + e;
    v = (k < 25) ? wih2[r * 25 + k] : 0.f;
  } else {                         // gate tiles: (kg*128 + row)*8 + e
    int j = i - 24576;
    int q = j / 16384, L = j % 16384;
    int kg = L >> 10, r = (L & 1023) >> 3, e = L & 7, k = kg * 8 + e;
    if (q < 3)       v = whh1[(q * 128 + r) * 128 + k];
    else if (q < 6)  v = whh2[((q - 3) * 128 + r) * 128 + k];
    else if (q < 12) { int q2 = q - 6;  v = wih3[((q2 % 3) * 128 + r) * 256 + (q2 / 3) * 128 + k]; }
    else if (q < 15) v = whh3[((q - 12) * 128 + r) * 128 + k];
    else if (q < 21) { int q4 = q - 15; v = wih4[((q4 % 3) * 128 + r) * 256 + (q4 / 3) * 128 + k]; }
    else             v = whh4[((q - 21) * 128 + r) * 128 + k];
  }
  g_ws[i] = f2b(v);
}

// ---------------- params ----------------
struct GruParams {
  const float* x;
  const float* bih[4];
  const float* bhh[4];
  const float* wfc[4];
  const float* bfc[4];
  float* out;        // [B][T][9]
  float* hf[4];      // [B][128]
  float* hT[4];      // [B][T][128]
};

// dynamic LDS layout (bytes)
#define L_WB0   0u
#define L_WB1   32768u
#define L_WB2   65536u
#define L_HFRAG 98304u     // ushort [2][4][16][16][8] = 32768 B
#define L_XA    131072u    // ushort [4][16][8] = 1024 B
#define L_FCW   132096u    // float [9][128] = 4608 B
#define SMEMB   136704u

__global__ __launch_bounds__(512) void gru_main(GruParams p) {
  extern __shared__ __align__(16) unsigned char smem[];
  unsigned short* wb0 = (unsigned short*)(smem + L_WB0);
  unsigned short* wb1 = (unsigned short*)(smem + L_WB1);
  unsigned short* wb2 = (unsigned short*)(smem + L_WB2);
  unsigned short* hbase = (unsigned short*)(smem + L_HFRAG);
  unsigned short* xbase = (unsigned short*)(smem + L_XA);
  float (*fcw)[128] = (float (*)[128])(smem + L_FCW);

  const int tid  = threadIdx.x;
  const int lane = tid & 63;
  const int wid  = tid >> 6;       // 0..7
  const int nlo  = lane & 15;
  const int khi  = lane >> 4;      // 0..3
  const int nh   = wid * 16 + nlo; // hidden column this lane owns
  const int b0   = blockIdx.x * 16;
  const int wgoff = khi * 1024 + nh * 8;   // gate-tile fragment base (ushorts)

  // prologue LDS fills
  for (int i = tid; i < 16384; i += 512) hbase[i] = 0;   // both hfrag buffers
  {
    int row = tid >> 5, col = tid & 31;                  // xa for t=0 (lai=0)
    float v = (col < 24) ? p.x[(size_t)(b0 + row) * (T_ * D_) + col] : 0.f;
    xbase[((col >> 3) * 16 + row) * 8 + (col & 7)] = f2b(v);
  }
  for (int i = tid; i < 9 * 128; i += 512) {             // FC weights -> LDS
    int rw = i >> 7, k = i & 127;
    const float* src; int lr;
    if (rw == 0)      { src = p.wfc[0]; lr = 0; }
    else if (rw < 4)  { src = p.wfc[1]; lr = rw - 1; }
    else if (rw < 7)  { src = p.wfc[2]; lr = rw - 4; }
    else              { src = p.wfc[3]; lr = rw - 7; }
    fcw[rw][k] = src[lr * H_ + k];
  }

  float hreg[4][4];
#pragma unroll
  for (int c = 0; c < 4; ++c)
#pragma unroll
    for (int q = 0; q < 4; ++q) hreg[c][q] = 0.f;

  float brz[4][2], bin[4], bhn[4];
#pragma unroll
  for (int c = 0; c < 4; ++c) {
    brz[c][0] = p.bih[c][nh] + p.bhh[c][nh];
    brz[c][1] = p.bih[c][128 + nh] + p.bhh[c][128 + nh];
    bin[c]    = p.bih[c][256 + nh];
    bhn[c]    = p.bhh[c][256 + nh];
  }

  // FC assignment: 144 threads = 16 rows x 9 outputs
  const bool fc_on = (tid < 144);
  const int foi = tid % 9;
  int frow = 0, fcell = 0;
  float fb = 0.f;
  if (fc_on) {
    frow = tid / 9;
    if (foi == 0)     { fcell = 0; fb = p.bfc[0][0]; }
    else if (foi < 4) { fcell = 1; fb = p.bfc[1][foi - 1]; }
    else if (foi < 7) { fcell = 2; fb = p.bfc[2][foi - 4]; }
    else              { fcell = 3; fb = p.bfc[3][foi - 7]; }
  }

  __syncthreads();
  // prime the pipeline: t0 -> wb0, t1 -> wb1
  dma_tile<3>(g_ws + 0, wb0, wid, lane);
  dma_tile<3>(g_ws + 12288, wb1, wid, lane);

  const f32x4 zf = {0.f, 0.f, 0.f, 0.f};

#define LDA4(dst, hb, C) do { \
  const unsigned short* s_ = (hb) + (C) * 2048; \
  _Pragma("unroll") \
  for (int kc = 0; kc < 4; ++kc) \
    (dst)[kc] = ldw(s_ + ((kc * 4 + khi) * 16 + nlo) * 8); \
} while (0)

#define FINISH(C, Rv, Zv, Iv, Hv) do { \
  unsigned short* hd = hob + (C) * 2048; \
  float* hTc = p.hT[C]; \
  _Pragma("unroll") \
  for (int q = 0; q < 4; ++q) { \
    int m = khi * 4 + q; \
    float r = sigmoidf_((Rv)[q] + brz[C][0]); \
    float z = sigmoidf_((Zv)[q] + brz[C][1]); \
    float n = tanhf_((Iv)[q] + bin[C] + r * ((Hv)[q] + bhn[C])); \
    float hnew = (1.f - z) * n + z * hreg[C][q]; \
    hreg[C][q] = hnew; \
    hd[((nh >> 3) * 16 + m) * 8 + (nh & 7)] = f2b(hnew); \
    hTc[(size_t)(b0 + m) * (T_ * H_) + (size_t)t * H_ + nh] = hnew; \
  } \
} while (0)

#define XG(buf, g) ldw((buf) + khi * 3072 + (g) * 1024 + nh * 8)

  for (int t = 0; t < T_; ++t) {
    const int ib = t & 1, ob = ib ^ 1;
    unsigned short* hib = hbase + ib * 8192;
    unsigned short* hob = hbase + ob * 8192;

    // P0 (t0=wih1p in wb0) -------------------------------------------------
    SYNC_V(3);
    dma_tile<4>(g_ws + TBQ(2), wb2, wid, lane);
    bf16x8 ax = ldw(xbase + (khi * 16 + nlo) * 8);
    f32x4 R1 = MFMA(ax, XG(wb0, 0), zf);
    f32x4 Z1 = MFMA(ax, XG(wb0, 1), zf);
    f32x4 I1 = MFMA(ax, XG(wb0, 2), zf);
    // P1 (t1=wih2p in wb1) -------------------------------------------------
    SYNC_V(4);
    dma_tile<4>(g_ws + TBQ(3), wb0, wid, lane);
    f32x4 R2 = MFMA(ax, XG(wb1, 0), zf);
    f32x4 Z2 = MFMA(ax, XG(wb1, 1), zf);
    f32x4 I2 = MFMA(ax, XG(wb1, 2), zf);
    // P2 (t2=whh1_r in wb2) ------------------------------------------------
    SYNC_V(4);
    dma_tile<4>(g_ws + TBQ(4), wb1, wid, lane);
    bf16x8 a1[4]; LDA4(a1, hib, 0);
    R1 = gtile(wb2, wgoff, a1, R1);
    // P3 (t3=whh1_z in wb0) ------------------------------------------------
    SYNC_V(4);
    dma_tile<4>(g_ws + TBQ(5), wb2, wid, lane);
    Z1 = gtile(wb0, wgoff, a1, Z1);
    // P4 (t4=whh1_n in wb1) ------------------------------------------------
    SYNC_V(4);
    dma_tile<4>(g_ws + TBQ(6), wb0, wid, lane);
    { f32x4 H1 = gtile(wb1, wgoff, a1, zf); FINISH(0, R1, Z1, I1, H1); }
    // P5 (t5=whh2_r in wb2) ------------------------------------------------
    SYNC_V(8);
    dma_tile<4>(g_ws + TBQ(7), wb1, wid, lane);
    bf16x8 a2[4]; LDA4(a2, hib, 1);
    R2 = gtile(wb2, wgoff, a2, R2);
    // P6 (t6=whh2_z in wb0) ------------------------------------------------
    SYNC_V(8);
    dma_tile<4>(g_ws + TBQ(8), wb2, wid, lane);
    Z2 = gtile(wb0, wgoff, a2, Z2);
    // P7 (t7=whh2_n in wb1) ------------------------------------------------
    SYNC_V(4);
    dma_tile<4>(g_ws + TBQ(9), wb0, wid, lane);
    { f32x4 H2 = gtile(wb1, wgoff, a2, zf); FINISH(1, R2, Z2, I2, H2); }
    // P8 (t8=w3_r_ka in wb2) -----------------------------------------------
    SYNC_V(8);
    dma_tile<4>(g_ws + TBQ(10), wb1, wid, lane);
    bf16x8 h1n[4]; LDA4(h1n, hob, 0);
    f32x4 R3 = gtile(wb2, wgoff, h1n, zf);
    // P9 (t9=w3_z_ka in wb0) -----------------------------------------------
    SYNC_V(8);
    dma_tile<4>(g_ws + TBQ(11), wb2, wid, lane);
    f32x4 Z3 = gtile(wb0, wgoff, h1n, zf);
    // P10 (t10=w3_n_ka in wb1) ---------------------------------------------
    SYNC_V(4);
    dma_tile<4>(g_ws + TBQ(12), wb0, wid, lane);
    f32x4 I3 = gtile(wb1, wgoff, h1n, zf);
    // P11 (t11=w3_r_kb in wb2) ---------------------------------------------
    SYNC_V(4);
    dma_tile<4>(g_ws + TBQ(13), wb1, wid, lane);
    bf16x8 h2n[4]; LDA4(h2n, hob, 1);
    R3 = gtile(wb2, wgoff, h2n, R3);
    // P12 (t12=w3_z_kb in wb0) ---------------------------------------------
    SYNC_V(4);
    dma_tile<4>(g_ws + TBQ(14), wb2, wid, lane);
    Z3 = gtile(wb0, wgoff, h2n, Z3);
    // P13 (t13=w3_n_kb in wb1) ---------------------------------------------
    SYNC_V(4);
    dma_tile<4>(g_ws + TBQ(15), wb0, wid, lane);
    I3 = gtile(wb1, wgoff, h2n, I3);
    // P14 (t14=whh3_r in wb2) ----------------------------------------------
    SYNC_V(4);
    dma_tile<4>(g_ws + TBQ(16), wb1, wid, lane);
    bf16x8 a3[4]; LDA4(a3, hib, 2);
    R3 = gtile(wb2, wgoff, a3, R3);
    // P15 (t15=whh3_z in wb0) ----------------------------------------------
    SYNC_V(4);
    dma_tile<4>(g_ws + TBQ(17), wb2, wid, lane);
    Z3 = gtile(wb0, wgoff, a3, Z3);
    // P16 (t16=whh3_n in wb1) ----------------------------------------------
    SYNC_V(4);
    dma_tile<4>(g_ws + TBQ(18), wb0, wid, lane);
    { f32x4 H3 = gtile(wb1, wgoff, a3, zf); FINISH(2, R3, Z3, I3, H3); }
    // P17 (t17=w4_r_ka in wb2) ---------------------------------------------
    SYNC_V(8);
    dma_tile<4>(g_ws + TBQ(19), wb1, wid, lane);
    f32x4 R4 = gtile(wb2, wgoff, h1n, zf);
    // P18 (t18=w4_z_ka in wb0) ---------------------------------------------
    SYNC_V(8);
    dma_tile<4>(g_ws + TBQ(20), wb2, wid, lane);
    f32x4 Z4 = gtile(wb0, wgoff, h1n, zf);
    // P19 (t19=w4_n_ka in wb1) ---------------------------------------------
    SYNC_V(4);
    dma_tile<4>(g_ws + TBQ(21), wb0, wid, lane);
    f32x4 I4 = gtile(wb1, wgoff, h1n, zf);
    // P20 (t20=w4_r_kb in wb2) ---------------------------------------------
    SYNC_V(4);
    dma_tile<4>(g_ws + TBQ(22), wb1, wid, lane);
    bf16x8 h3n[4]; LDA4(h3n, hob, 2);
    R4 = gtile(wb2, wgoff, h3n, R4);
    // P21 (t21=w4_z_kb in wb0) ---------------------------------------------
    SYNC_V(4);
    dma_tile<4>(g_ws + TBQ(23), wb2, wid, lane);
    Z4 = gtile(wb0, wgoff, h3n, Z4);
    // P22 (t22=w4_n_kb in wb1) ---------------------------------------------
    SYNC_V(4);
    dma_tile<4>(g_ws + TBQ(24), wb0, wid, lane);
    I4 = gtile(wb1, wgoff, h3n, I4);
    // P23 (t23=whh4_r in wb2) ----------------------------------------------
    SYNC_V(4);
    dma_tile<4>(g_ws + TBQ(25), wb1, wid, lane);
    bf16x8 a4[4]; LDA4(a4, hib, 3);
    R4 = gtile(wb2, wgoff, a4, R4);
    // P24 (t24=whh4_z in wb0; no DMA) --------------------------------------
    SYNC_V(4);
    Z4 = gtile(wb0, wgoff, a4, Z4);
    // P25 (t25=whh4_n in wb1; DMA t0' -> wb0) ------------------------------
    SYNC_V(0);
    dma_tile<3>(g_ws + 0, wb0, wid, lane);
    { f32x4 H4 = gtile(wb1, wgoff, a4, zf); FINISH(3, R4, Z4, I4, H4); }
    // P26 (FC + lai + x staging; DMA t1' -> wb1) ---------------------------
    SYNC_NV();
    dma_tile<3>(g_ws + 12288, wb1, wid, lane);
    if (fc_on) {
      const unsigned short* hb = hbase + ob * 8192 + fcell * 2048 + frow * 8;
      float acc = fb;
#pragma unroll
      for (int kg = 0; kg < 16; ++kg) {
        bf16x8 hv = ldw(hb + kg * 128);
        float4 wA = *(const float4*)&fcw[foi][kg * 8];
        float4 wB = *(const float4*)&fcw[foi][kg * 8 + 4];
        float a0 = __uint_as_float(((unsigned)(unsigned short)hv[0]) << 16);
        float a1_ = __uint_as_float(((unsigned)(unsigned short)hv[1]) << 16);
        float a2_ = __uint_as_float(((unsigned)(unsigned short)hv[2]) << 16);
        float a3_ = __uint_as_float(((unsigned)(unsigned short)hv[3]) << 16);
        float a4_ = __uint_as_float(((unsigned)(unsigned short)hv[4]) << 16);
        float a5_ = __uint_as_float(((unsigned)(unsigned short)hv[5]) << 16);
        float a6_ = __uint_as_float(((unsigned)(unsigned short)hv[6]) << 16);
        float a7_ = __uint_as_float(((unsigned)(unsigned short)hv[7]) << 16);
        acc += a0 * wA.x + a1_ * wA.y + a2_ * wA.z + a3_ * wA.w +
               a4_ * wB.x + a5_ * wB.y + a6_ * wB.z + a7_ * wB.w;
      }
      p.out[(size_t)(b0 + frow) * (T_ * 9) + t * 9 + foi] = acc;
      if (foi == 7) xbase[(3 * 16 + frow) * 8 + 0] = f2b(acc);   // lai
    } else if (tid >= 256 && t + 1 < T_) {
      for (int i2 = tid - 256; i2 < 16 * 24; i2 += 256) {
        int row = i2 / 24, col = i2 % 24;
        xbase[((col >> 3) * 16 + row) * 8 + (col & 7)] =
            f2b(p.x[(size_t)(b0 + row) * (T_ * D_) + (size_t)(t + 1) * D_ + col]);
      }
    }
  }

  // final hidden states (fp32 register carry)
#pragma unroll
  for (int c = 0; c < 4; ++c)
#pragma unroll
    for (int q = 0; q < 4; ++q)
      p.hf[c][(size_t)(b0 + khi * 4 + q) * H_ + nh] = hreg[c][q];
}

// ---------------- launcher ----------------
extern "C" void kernel_launch(void* const* d_in, const int* in_sizes, int n_in,
                              void* d_out, int out_size, void* d_ws, size_t ws_size,
                              hipStream_t stream) {
  (void)in_sizes; (void)n_in; (void)d_ws; (void)ws_size; (void)out_size;
  const float* x    = (const float*)d_in[0];
  const float* wih1 = (const float*)d_in[1];
  const float* whh1 = (const float*)d_in[2];
  const float* wih2 = (const float*)d_in[7];
  const float* whh2 = (const float*)d_in[8];
  const float* wih3 = (const float*)d_in[13];
  const float* whh3 = (const float*)d_in[14];
  const float* wih4 = (const float*)d_in[19];
  const float* whh4 = (const float*)d_in[20];

  prep_weights<<<(WS_ELEMS + 255) / 256, 256, 0, stream>>>(wih1, wih2, whh1, whh2,
                                                           whh3, whh4, wih3, wih4);

  GruParams p;
  p.x = x;
  for (int c = 0; c < 4; ++c) {
    p.bih[c] = (const float*)d_in[3 + 6 * c];
    p.bhh[c] = (const float*)d_in[4 + 6 * c];
    p.wfc[c] = (const float*)d_in[5 + 6 * c];
    p.bfc[c] = (const float*)d_in[6 + 6 * c];
  }
  float* out = (float*)d_out;
  p.out = out;                                    // B*T*9
  const size_t HF_OFF = (size_t)B_ * T_ * 9;
  const size_t HT_OFF = HF_OFF + 4ull * B_ * H_;
  const size_t HT_SZ  = (size_t)B_ * T_ * H_;
  for (int c = 0; c < 4; ++c) {
    p.hf[c] = out + HF_OFF + (size_t)c * B_ * H_;
    p.hT[c] = out + HT_OFF + (size_t)c * HT_SZ;
  }

  hipFuncSetAttribute(reinterpret_cast<const void*>(gru_main),
                      hipFuncAttributeMaxDynamicSharedMemorySize, (int)SMEMB);
  gru_main<<<64, 512, SMEMB, stream>>>(p);
}

// Round 7
// 8927.303 us; speedup vs baseline: 1.7306x; 1.1021x over previous
//
#include <hip/hip_runtime.h>
#include <hip/hip_bf16.h>

// ---------------- problem constants ----------------
#define B_   1024
#define T_   365
#define D_   24
#define H_   128

// g_ws: bf16 weights, fragment-major TILE order (26 tiles):
//  t0: wih1p [k32 x 384rows] 24KB   t1: wih2p 24KB (k=24 -> lai col)
//  t2-4: whh1 r/z/n [16 kg][128 row][8 e] 32KB each; t5-7: whh2
//  t8-13: wih3 (ka r,z,n | kb r,z,n); t14-16: whh3
//  t17-22: wih4 (ka | kb); t23-25: whh4
#define WS_ELEMS 417792
#define TBQ(q) (24576 + ((q) - 2) * 16384)

typedef __attribute__((ext_vector_type(8))) short bf16x8;
typedef __attribute__((ext_vector_type(4))) float f32x4;

__device__ __align__(16) unsigned short g_ws[WS_ELEMS];

#define MFMA(a, b, c) __builtin_amdgcn_mfma_f32_16x16x32_bf16((a), (b), (c), 0, 0, 0)

// counted-vmcnt phase sync: wait own tile loads, raw barrier (no full drain)
#define SYNC_V(N) do { \
  __builtin_amdgcn_sched_barrier(0); \
  asm volatile("s_waitcnt vmcnt(" #N ") lgkmcnt(0)" ::: "memory"); \
  __builtin_amdgcn_s_barrier(); \
  __builtin_amdgcn_sched_barrier(0); \
} while (0)

#define SYNC_NV() do { \
  __builtin_amdgcn_sched_barrier(0); \
  asm volatile("s_waitcnt lgkmcnt(0)" ::: "memory"); \
  __builtin_amdgcn_s_barrier(); \
  __builtin_amdgcn_sched_barrier(0); \
} while (0)

__device__ __forceinline__ bf16x8 ldw(const unsigned short* p) {
  return *(const bf16x8*)p;
}
__device__ __forceinline__ unsigned short f2b(float f) {
  union { __hip_bfloat16 h; unsigned short u; } cv;
  cv.h = __float2bfloat16(f);   // RNE
  return cv.u;
}
__device__ __forceinline__ float b2f(unsigned short u) {
  union { float f; unsigned int u32; } cv;
  cv.u32 = ((unsigned int)u) << 16;
  return cv.f;
}
__device__ __forceinline__ float sigmoidf_(float x) { return 1.f / (1.f + __expf(-x)); }
__device__ __forceinline__ float tanhf_(float x) {
  float e = __expf(2.f * x);
  return 1.f - 2.f / (e + 1.f);
}

// async DMA: wave wid copies NCH KB, linear; lane contributes 16B per instr
template <int NCH>
__device__ __forceinline__ void dma_tile(const unsigned short* gsrc, unsigned short* lbuf,
                                         int wid, int lane) {
  const char* g = (const char*)gsrc + wid * (NCH * 1024) + lane * 16;
  char* l = (char*)lbuf + wid * (NCH * 1024);
#pragma unroll
  for (int j = 0; j < NCH; ++j)
    __builtin_amdgcn_global_load_lds(
        (const __attribute__((address_space(1))) void*)(g + j * 1024),
        (__attribute__((address_space(3))) void*)(l + j * 1024), 16, 0, 0);
}

// 4-MFMA gate-tile accumulate
__device__ __forceinline__ f32x4 gtile(const unsigned short* buf, int woff,
                                       const bf16x8* a, f32x4 acc) {
#pragma unroll
  for (int kc = 0; kc < 4; ++kc)
    acc = MFMA(a[kc], *(const bf16x8*)(buf + woff + kc * 4096), acc);
  return acc;
}

// ---------------- prologue: fp32 -> fragment-major bf16 tiles ----------------
__global__ void prep_weights(const float* wih1, const float* wih2,
                             const float* whh1, const float* whh2,
                             const float* whh3, const float* whh4,
                             const float* wih3, const float* wih4) {
  int i = blockIdx.x * blockDim.x + threadIdx.x;
  if (i >= WS_ELEMS) return;
  float v = 0.f;
  if (i < 12288) {                 // t0: (kg*384 + row)*8 + e
    int kg = i / 3072, rem = i % 3072, r = rem >> 3, e = rem & 7, k = kg * 8 + e;
    v = (k < 24) ? wih1[r * 24 + k] : 0.f;
  } else if (i < 24576) {          // t1
    int j = i - 12288;
    int kg = j / 3072, rem = j % 3072, r = rem >> 3, e = rem & 7, k = kg * 8 + e;
    v = (k < 25) ? wih2[r * 25 + k] : 0.f;
  } else {                         // gate tiles: (kg*128 + row)*8 + e
    int j = i - 24576;
    int q = j / 16384, L = j % 16384;
    int kg = L >> 10, r = (L & 1023) >> 3, e = L & 7, k = kg * 8 + e;
    if (q < 3)       v = whh1[(q * 128 + r) * 128 + k];
    else if (q < 6)  v = whh2[((q - 3) * 128 + r) * 128 + k];
    else if (q < 12) { int q2 = q - 6;  v = wih3[((q2 % 3) * 128 + r) * 256 + (q2 / 3) * 128 + k]; }
    else if (q < 15) v = whh3[((q - 12) * 128 + r) * 128 + k];
    else if (q < 21) { int q4 = q - 15; v = wih4[((q4 % 3) * 128 + r) * 256 + (q4 / 3) * 128 + k]; }
    else             v = whh4[((q - 21) * 128 + r) * 128 + k];
  }
  g_ws[i] = f2b(v);
}

// ---------------- params ----------------
struct GruParams {
  const float* x;
  const float* bih[4];
  const float* bhh[4];
  const float* wfc[4];
  const float* bfc[4];
  float* out;        // [B][T][9]
  float* hf[4];      // [B][128]
  float* hT[4];      // [B][T][128]
};

// dynamic LDS layout (bytes)
#define L_PB0   0u
#define L_PB1   32768u
#define L_PB2   65536u
#define L_PB3   98304u
#define L_HF    131072u    // ushort [4][16][16][8] = 16384
#define L_XF    147456u    // float [2][16][24] = 3072
#define L_LAI   150528u    // float [16] = 64
#define L_FCW   150592u    // float [9][128] = 4608
#define SMEMB   155200u

__global__ __launch_bounds__(512) void gru_main(GruParams p) {
  extern __shared__ __align__(16) unsigned char smem[];
  unsigned short* pb0 = (unsigned short*)(smem + L_PB0);
  unsigned short* pb1 = (unsigned short*)(smem + L_PB1);
  unsigned short* pb2 = (unsigned short*)(smem + L_PB2);
  unsigned short* pb3 = (unsigned short*)(smem + L_PB3);
  unsigned short* hfr = (unsigned short*)(smem + L_HF);
  float* xfb = (float*)(smem + L_XF);          // [2][16][24]
  float* lai_s = (float*)(smem + L_LAI);
  float (*fcw)[128] = (float (*)[128])(smem + L_FCW);

  const int tid  = threadIdx.x;
  const int lane = tid & 63;
  const int wid  = tid >> 6;       // 0..7
  const int nlo  = lane & 15;
  const int khi  = lane >> 4;      // 0..3
  const int nh   = wid * 16 + nlo;
  const int b0   = blockIdx.x * 16;
  const int wgoff = khi * 1024 + nh * 8;     // gate-tile fragment base (ushorts)
  const int xwoff = khi * 3072 + nh * 8;     // x-weight-tile fragment base

  // ---- prologue LDS fills ----
  for (int i = tid; i < 8192; i += 512) hfr[i] = 0;
  if (tid < 16) lai_s[tid] = 0.f;
  for (int i = tid; i < 9 * 128; i += 512) {
    int rw = i >> 7, k = i & 127;
    const float* src; int lr;
    if (rw == 0)      { src = p.wfc[0]; lr = 0; }
    else if (rw < 4)  { src = p.wfc[1]; lr = rw - 1; }
    else if (rw < 7)  { src = p.wfc[2]; lr = rw - 4; }
    else              { src = p.wfc[3]; lr = rw - 7; }
    fcw[rw][k] = src[lr * H_ + k];
  }

  float hreg[4][4];
#pragma unroll
  for (int c = 0; c < 4; ++c)
#pragma unroll
    for (int q = 0; q < 4; ++q) hreg[c][q] = 0.f;

  float brz[4][2], bin[4], bhn[4];
#pragma unroll
  for (int c = 0; c < 4; ++c) {
    brz[c][0] = p.bih[c][nh] + p.bhh[c][nh];
    brz[c][1] = p.bih[c][128 + nh] + p.bhh[c][128 + nh];
    bin[c]    = p.bih[c][256 + nh];
    bhn[c]    = p.bhh[c][256 + nh];
  }

  // x DMA: 96 chunks of 16B per step; wave w handles chunks w*12..w*12+11 (lanes 0..11)
  const int chunk = wid * 12 + (lane < 12 ? lane : 11);
  const int xrow = chunk / 6, xoff = (chunk % 6) * 16;
  const char* xsrc = (const char*)(p.x + (size_t)(b0 + xrow) * (T_ * D_)) + xoff;
  char* xd0 = (char*)xfb + chunk * 16;
  char* xd1 = (char*)xfb + 1536 + chunk * 16;

  // FC assignment: 144 threads = 16 rows x 9 outputs
  const bool fc_on = (tid < 144);
  const int foi = tid % 9;
  int frow = 0, fcell = 0;
  float fb = 0.f;
  if (fc_on) {
    frow = tid / 9;
    if (foi == 0)     { fcell = 0; fb = p.bfc[0][0]; }
    else if (foi < 4) { fcell = 1; fb = p.bfc[1][foi - 1]; }
    else if (foi < 7) { fcell = 2; fb = p.bfc[2][foi - 4]; }
    else              { fcell = 3; fb = p.bfc[3][foi - 7]; }
  }

  __syncthreads();
  // prime: t0->pb0, t1->pb1, t2->pb2, x(t=0)->xf[0]; full drain once
  dma_tile<3>(g_ws + 0, pb0, wid, lane);
  dma_tile<3>(g_ws + 12288, pb1, wid, lane);
  dma_tile<4>(g_ws + TBQ(2), pb2, wid, lane);
  if (lane < 12)
    __builtin_amdgcn_global_load_lds(
        (const __attribute__((address_space(1))) void*)xsrc,
        (__attribute__((address_space(3))) void*)xd0, 16, 0, 0);
  xsrc += D_ * 4;   // now points at t=1
  asm volatile("s_waitcnt vmcnt(0) lgkmcnt(0)" ::: "memory");
  __builtin_amdgcn_s_barrier();

  const f32x4 zf = {0.f, 0.f, 0.f, 0.f};

#define LDA4(dst, C) do { \
  const unsigned short* s_ = hfr + (C) * 2048; \
  _Pragma("unroll") \
  for (int kc_ = 0; kc_ < 4; ++kc_) \
    (dst)[kc_] = ldw(s_ + ((kc_ * 4 + khi) * 16 + nlo) * 8); \
} while (0)

#define FINISH(C, Rv, Zv, Iv, Hv) do { \
  unsigned short* hd_ = hfr + (C) * 2048; \
  _Pragma("unroll") \
  for (int q_ = 0; q_ < 4; ++q_) { \
    int m_ = khi * 4 + q_; \
    float r_ = sigmoidf_((Rv)[q_] + brz[C][0]); \
    float z_ = sigmoidf_((Zv)[q_] + brz[C][1]); \
    float n_ = tanhf_((Iv)[q_] + bin[C] + r_ * ((Hv)[q_] + bhn[C])); \
    float hn_ = (1.f - z_) * n_ + z_ * hreg[C][q_]; \
    hreg[C][q_] = hn_; \
    hd_[((nh >> 3) * 16 + m_) * 8 + (nh & 7)] = f2b(hn_); \
  } \
} while (0)

#define DMA4(q, dst) dma_tile<4>(g_ws + TBQ(q), (dst), wid, lane)

  for (int t = 0; t < T_; ++t) {
    const float* xf = xfb + (t & 1) * 384;   // [16][24] f32 for this step

    // P0 (t0=wih1p in pb0)
    SYNC_V(23);
    DMA4(3, pb3);
    bf16x8 ax;
    if (khi < 3) {
      const float* xp = xf + nlo * 24 + khi * 8;
      float4 lo = *(const float4*)xp;
      float4 hi = *(const float4*)(xp + 4);
      ax[0] = (short)f2b(lo.x); ax[1] = (short)f2b(lo.y);
      ax[2] = (short)f2b(lo.z); ax[3] = (short)f2b(lo.w);
      ax[4] = (short)f2b(hi.x); ax[5] = (short)f2b(hi.y);
      ax[6] = (short)f2b(hi.z); ax[7] = (short)f2b(hi.w);
    } else {
      ax = (bf16x8){0, 0, 0, 0, 0, 0, 0, 0};
      ax[0] = (short)f2b(lai_s[nlo]);
    }
    f32x4 R1 = MFMA(ax, ldw(pb0 + xwoff), zf);
    f32x4 Z1 = MFMA(ax, ldw(pb0 + xwoff + 1024), zf);
    f32x4 I1 = MFMA(ax, ldw(pb0 + xwoff + 2048), zf);
    // P1 (t1=wih2p in pb1)
    SYNC_V(24);
    DMA4(4, pb0);
    f32x4 R2 = MFMA(ax, ldw(pb1 + xwoff), zf);
    f32x4 Z2 = MFMA(ax, ldw(pb1 + xwoff + 1024), zf);
    f32x4 I2 = MFMA(ax, ldw(pb1 + xwoff + 2048), zf);
    // P2 (t2=whh1_r in pb2)
    SYNC_V(24);
    DMA4(5, pb1);
    bf16x8 a1[4]; LDA4(a1, 0);
    R1 = gtile(pb2, wgoff, a1, R1);
    // P3 (t3=whh1_z in pb3)
    SYNC_V(8);
    DMA4(6, pb2);
    Z1 = gtile(pb3, wgoff, a1, Z1);
    // P4 (t4=whh1_n in pb0) + x prefetch for t+1
    SYNC_V(8);
    DMA4(7, pb3);
    if (t + 1 < T_) {
      char* xd = ((t + 1) & 1) ? xd1 : xd0;
      if (lane < 12)
        __builtin_amdgcn_global_load_lds(
            (const __attribute__((address_space(1))) void*)xsrc,
            (__attribute__((address_space(3))) void*)xd, 16, 0, 0);
    }
    { f32x4 H1 = gtile(pb0, wgoff, a1, zf); FINISH(0, R1, Z1, I1, H1); }
    // P5 (t5=whh2_r in pb1)
    SYNC_V(9);
    DMA4(8, pb0);
    bf16x8 a2[4]; LDA4(a2, 1);
    R2 = gtile(pb1, wgoff, a2, R2);
    // P6 (t6=whh2_z in pb2)
    SYNC_V(9);
    DMA4(9, pb1);
    Z2 = gtile(pb2, wgoff, a2, Z2);
    // P7 (t7=whh2_n in pb3)
    SYNC_V(9);
    DMA4(10, pb2);
    { f32x4 H2 = gtile(pb3, wgoff, a2, zf); FINISH(1, R2, Z2, I2, H2); }
    // P8 (t8=w3_r_ka in pb0)
    SYNC_V(8);
    DMA4(11, pb3);
    bf16x8 h1n[4]; LDA4(h1n, 0);
    f32x4 R3 = gtile(pb0, wgoff, h1n, zf);
    // P9 (t9=w3_z_ka in pb1)
    SYNC_V(8);
    DMA4(12, pb0);
    f32x4 Z3 = gtile(pb1, wgoff, h1n, zf);
    // P10 (t10=w3_n_ka in pb2)
    SYNC_V(8);
    DMA4(13, pb1);
    f32x4 I3 = gtile(pb2, wgoff, h1n, zf);
    // P11 (t11=w3_r_kb in pb3)
    SYNC_V(8);
    DMA4(14, pb2);
    bf16x8 h2n[4]; LDA4(h2n, 1);
    R3 = gtile(pb3, wgoff, h2n, R3);
    // P12 (t12=w3_z_kb in pb0)
    SYNC_V(8);
    DMA4(15, pb3);
    Z3 = gtile(pb0, wgoff, h2n, Z3);
    // P13 (t13=w3_n_kb in pb1)
    SYNC_V(8);
    DMA4(16, pb0);
    I3 = gtile(pb1, wgoff, h2n, I3);
    // P14 (t14=whh3_r in pb2)
    SYNC_V(8);
    DMA4(17, pb1);
    bf16x8 a3[4]; LDA4(a3, 2);
    R3 = gtile(pb2, wgoff, a3, R3);
    // P15 (t15=whh3_z in pb3)
    SYNC_V(8);
    DMA4(18, pb2);
    Z3 = gtile(pb3, wgoff, a3, Z3);
    // P16 (t16=whh3_n in pb0)
    SYNC_V(8);
    DMA4(19, pb3);
    { f32x4 H3 = gtile(pb0, wgoff, a3, zf); FINISH(2, R3, Z3, I3, H3); }
    // P17 (t17=w4_r_ka in pb1)
    SYNC_V(8);
    DMA4(20, pb0);
    f32x4 R4 = gtile(pb1, wgoff, h1n, zf);
    // P18 (t18=w4_z_ka in pb2)
    SYNC_V(8);
    DMA4(21, pb1);
    f32x4 Z4 = gtile(pb2, wgoff, h1n, zf);
    // P19 (t19=w4_n_ka in pb3)
    SYNC_V(8);
    DMA4(22, pb2);
    f32x4 I4 = gtile(pb3, wgoff, h1n, zf);
    // P20 (t20=w4_r_kb in pb0)
    SYNC_V(8);
    DMA4(23, pb3);
    bf16x8 h3n[4]; LDA4(h3n, 2);
    R4 = gtile(pb0, wgoff, h3n, R4);
    // P21 (t21=w4_z_kb in pb1)
    SYNC_V(8);
    DMA4(24, pb0);
    Z4 = gtile(pb1, wgoff, h3n, Z4);
    // P22 (t22=w4_n_kb in pb2)
    SYNC_V(8);
    DMA4(25, pb1);
    I4 = gtile(pb2, wgoff, h3n, I4);
    // P23 (t23=whh4_r in pb3); issue next-step t0 -> pb2
    SYNC_V(8);
    dma_tile<3>(g_ws + 0, pb2, wid, lane);
    bf16x8 a4[4]; LDA4(a4, 3);
    R4 = gtile(pb3, wgoff, a4, R4);
    // P24 (t24=whh4_z in pb0); issue next-step t1 -> pb3
    SYNC_V(7);
    dma_tile<3>(g_ws + 12288, pb3, wid, lane);
    Z4 = gtile(pb0, wgoff, a4, Z4);
    // P25 (t25=whh4_n in pb1); issue next-step t2 -> pb0
    SYNC_V(6);
    DMA4(2, pb0);
    { f32x4 H4 = gtile(pb1, wgoff, a4, zf); FINISH(3, R4, Z4, I4, H4); }

    // ===== FC phase: hT stores + FC heads + lai =====
    SYNC_NV();
#pragma unroll
    for (int c = 0; c < 4; ++c)
#pragma unroll
      for (int q = 0; q < 4; ++q)
        p.hT[c][(size_t)(b0 + khi * 4 + q) * (T_ * H_) + (size_t)t * H_ + nh] = hreg[c][q];
    if (fc_on) {
      const unsigned short* hb = hfr + fcell * 2048 + frow * 8;
      float acc = fb;
#pragma unroll
      for (int kg = 0; kg < 16; ++kg) {
        bf16x8 hv = ldw(hb + kg * 128);
        float4 wA = *(const float4*)&fcw[foi][kg * 8];
        float4 wB = *(const float4*)&fcw[foi][kg * 8 + 4];
        acc += b2f((unsigned short)hv[0]) * wA.x + b2f((unsigned short)hv[1]) * wA.y +
               b2f((unsigned short)hv[2]) * wA.z + b2f((unsigned short)hv[3]) * wA.w +
               b2f((unsigned short)hv[4]) * wB.x + b2f((unsigned short)hv[5]) * wB.y +
               b2f((unsigned short)hv[6]) * wB.z + b2f((unsigned short)hv[7]) * wB.w;
      }
      p.out[(size_t)(b0 + frow) * (T_ * 9) + t * 9 + foi] = acc;
      if (foi == 7) lai_s[frow] = acc;   // o4 col 0 -> lai for next step
    }
    xsrc += D_ * 4;
    // rotate stream buffers: tile index advances 26 == 2 (mod 4)
    { unsigned short* tp;
      tp = pb0; pb0 = pb2; pb2 = tp;
      tp = pb1; pb1 = pb3; pb3 = tp; }
  }

  asm volatile("s_waitcnt vmcnt(0)" ::: "memory");   // retire dangling prefetches

  // final hidden states (fp32 register carry)
#pragma unroll
  for (int c = 0; c < 4; ++c)
#pragma unroll
    for (int q = 0; q < 4; ++q)
      p.hf[c][(size_t)(b0 + khi * 4 + q) * H_ + nh] = hreg[c][q];
}

// ---------------- launcher ----------------
extern "C" void kernel_launch(void* const* d_in, const int* in_sizes, int n_in,
                              void* d_out, int out_size, void* d_ws, size_t ws_size,
                              hipStream_t stream) {
  (void)in_sizes; (void)n_in; (void)d_ws; (void)ws_size; (void)out_size;
  const float* x    = (const float*)d_in[0];
  const float* wih1 = (const float*)d_in[1];
  const float* whh1 = (const float*)d_in[2];
  const float* wih2 = (const float*)d_in[7];
  const float* whh2 = (const float*)d_in[8];
  const float* wih3 = (const float*)d_in[13];
  const float* whh3 = (const float*)d_in[14];
  const float* wih4 = (const float*)d_in[19];
  const float* whh4 = (const float*)d_in[20];

  prep_weights<<<(WS_ELEMS + 255) / 256, 256, 0, stream>>>(wih1, wih2, whh1, whh2,
                                                           whh3, whh4, wih3, wih4);

  GruParams p;
  p.x = x;
  for (int c = 0; c < 4; ++c) {
    p.bih[c] = (const float*)d_in[3 + 6 * c];
    p.bhh[c] = (const float*)d_in[4 + 6 * c];
    p.wfc[c] = (const float*)d_in[5 + 6 * c];
    p.bfc[c] = (const float*)d_in[6 + 6 * c];
  }
  float* out = (float*)d_out;
  p.out = out;
  const size_t HF_OFF = (size_t)B_ * T_ * 9;
  const size_t HT_OFF = HF_OFF + 4ull * B_ * H_;
  const size_t HT_SZ  = (size_t)B_ * T_ * H_;
  for (int c = 0; c < 4; ++c) {
    p.hf[c] = out + HF_OFF + (size_t)c * B_ * H_;
    p.hT[c] = out + HT_OFF + (size_t)c * HT_SZ;
  }

  hipFuncSetAttribute(reinterpret_cast<const void*>(gru_main),
                      hipFuncAttributeMaxDynamicSharedMemorySize, (int)SMEMB);
  gru_main<<<64, 512, SMEMB, stream>>>(p);
}